// Round 3
// baseline (3647.193 us; speedup 1.0000x reference)
//
#include <hip/hip_runtime.h>
#include <hip/hip_bf16.h>
#include <stdint.h>

// Problem constants: B=16, T=256 (teacher uses T-1=255), LAT=512, U=1024, V=32000, E=256
#define U3 3072

// ---------------- workspace layout (bytes) ----------------
#define XPROJ_BYTES (16u*255u*3072u*4u)         /* 48,107,520  f32 x_proj          */
#define WS_XPROJ    0u
#define RT_BYTES    (3072u*1024u*4u)            /* 12,582,912  f32 R transposed    */
#define WS_RT       (WS_XPROJ + XPROJ_BYTES)
#define H_BYTES     (2u*16u*1024u*4u)           /* h ping-pong                     */
#define WS_H        (WS_RT + RT_BYTES)
#define GOUT_BYTES  (4096u*1024u*2u)            /* gru_out bf16, padded to 4096 rows */
#define WS_GOUT     (WS_H + H_BYTES)
#define Y_BYTES     (16u*1024u*4u)              /* y carry, f32                    */
#define WS_Y        (WS_GOUT + GOUT_BYTES)
// total ~69.3 MB

typedef __attribute__((ext_vector_type(8))) short s16x8;
typedef __attribute__((ext_vector_type(4))) float f32x4;

__device__ __forceinline__ unsigned short f2bf(float x) {
  union { float f; unsigned u; } v; v.f = x;
  unsigned r = v.u + 0x7FFFu + ((v.u >> 16) & 1u);   // round-to-nearest-even
  return (unsigned short)(r >> 16);
}
// LDS bank swizzle: XOR bits 5-7 of float-index into bits 2-4 (moves 16B granules)
__device__ __forceinline__ int swz(int idx) { return idx ^ (((idx >> 5) & 7) << 2); }

// ---------------- K0: transpose gru_rkernel [1024][3072] -> RT [3072][1024] ----------------
__global__ __launch_bounds__(256) void k_transpose(const float* __restrict__ R,
                                                   float* __restrict__ RT) {
  __shared__ float tile[32][33];
  const int cb = blockIdx.x * 32;   // over 3072
  const int kb = blockIdx.y * 32;   // over 1024
  const int c = threadIdx.x & 31;
  const int r0 = threadIdx.x >> 5;  // 0..7
#pragma unroll
  for (int i = 0; i < 4; ++i) {
    int r = r0 + i * 8;
    tile[r][c] = R[(size_t)(kb + r) * U3 + cb + c];
  }
  __syncthreads();
#pragma unroll
  for (int i = 0; i < 4; ++i) {
    int r = r0 + i * 8;
    RT[(size_t)(cb + r) * 1024 + kb + c] = tile[c][r];
  }
}

// ---------------- K1: h0 = latent @ dense_W + dense_b ----------------
__global__ __launch_bounds__(256) void k_h0(const float* __restrict__ lat,
                                            const float* __restrict__ dW,
                                            const float* __restrict__ db,
                                            float* __restrict__ H) {
  const int b = blockIdx.x >> 2;
  const int u = ((blockIdx.x & 3) << 8) + threadIdx.x;
  float acc = db[u];
#pragma unroll 4
  for (int l2 = 0; l2 < 512; ++l2)
    acc = fmaf(lat[b * 512 + l2], dW[(size_t)l2 * 1024 + u], acc);
  H[b * 1024 + u] = acc;
}

// ---------------- K2: x_proj = emb[teacher] @ gru_kernel + gru_bias[0] ----------------
// grid (6, 255), block 128.  Tile: 16 rows x 512 cols, K=256.
__global__ __launch_bounds__(128) void k_xproj(const int* __restrict__ tok,
                                               const float* __restrict__ emb,
                                               const float* __restrict__ gk,
                                               const float* __restrict__ gbias,
                                               float* __restrict__ xp) {
  __shared__ float elds[16][256];
  __shared__ int toks[16];
  const int tid = threadIdx.x;
  const int c0 = blockIdx.x * 512;
  const int r0 = blockIdx.y * 16;
  if (tid < 16) {
    int grow = r0 + tid;
    int b = grow / 255;
    int t = grow - b * 255;
    toks[tid] = tok[b * 256 + t];
  }
  __syncthreads();
#pragma unroll
  for (int i = 0; i < 8; ++i) {
    int q = tid + i * 128;
    int r = q >> 6;
    int kq = (q & 63) << 2;
    *(float4*)&elds[r][kq] = *(const float4*)&emb[(size_t)toks[r] * 256 + kq];
  }
  __syncthreads();
  float acc[16][4];
#pragma unroll
  for (int r = 0; r < 16; ++r)
#pragma unroll
    for (int u = 0; u < 4; ++u) acc[r][u] = 0.f;
  const int c = c0 + tid;
#pragma unroll 2
  for (int k = 0; k < 256; ++k) {
    const float* g = &gk[(size_t)k * U3 + c];
    float w0 = g[0], w1 = g[128], w2 = g[256], w3 = g[384];
#pragma unroll
    for (int r = 0; r < 16; ++r) {
      float e = elds[r][k];
      acc[r][0] = fmaf(e, w0, acc[r][0]);
      acc[r][1] = fmaf(e, w1, acc[r][1]);
      acc[r][2] = fmaf(e, w2, acc[r][2]);
      acc[r][3] = fmaf(e, w3, acc[r][3]);
    }
  }
  float b0 = gbias[c], b1_ = gbias[c + 128], b2 = gbias[c + 256], b3 = gbias[c + 384];
#pragma unroll
  for (int r = 0; r < 16; ++r) {
    float* o = &xp[(size_t)(r0 + r) * U3 + c];
    o[0]   = acc[r][0] + b0;
    o[128] = acc[r][1] + b1_;
    o[256] = acc[r][2] + b2;
    o[384] = acc[r][3] + b3;
  }
}

// ---------------- K3: one GRU timestep (launched 255x; kernel boundary = global sync) ----
// 256 WGs x 256 thr. WG w owns u-cols [4w,4w+4) = 12 gate-cols; R-slice (48KB) staged in LDS
// (L2-hot across launches since WG->XCD mapping is deterministic). h read global->reg.
// 64-way k-split dot -> 4-phase LDS reduction -> gates on 16 lanes/phase -> global h/y.
__global__ __launch_bounds__(256) void k_step(
    const float* __restrict__ RT, const float* __restrict__ xproj,
    const float* __restrict__ gbias, const int* __restrict__ tok,
    const float* __restrict__ Hin, float* __restrict__ Hout,
    float* __restrict__ Ybuf, unsigned short* __restrict__ gout, int t) {
  __shared__ float Rl[12288];        // [12][1024], swizzled (48 KB)
  __shared__ float Red[4 * 64 * 12]; // [bq][kl][12]          (12 KB)

  const int tid = threadIdx.x;
  const int wg  = blockIdx.x;
  const int kl  = tid & 63;
  const int bq  = tid >> 6;          // wave id = batch quad
  const int u0  = wg << 2;

  // stage R slice (cl = ul*3 + g -> RT row g*1024 + u0 + ul)
#pragma unroll
  for (int cl = 0; cl < 12; ++cl) {
    int gcol = (cl % 3) * 1024 + u0 + cl / 3;
    *(float4*)&Rl[swz(cl * 1024 + tid * 4)] =
        *(const float4*)&RT[(size_t)gcol * 1024 + tid * 4];
  }

  // load this thread's h window: 4 batches x 16 k, direct global->reg
  float4 hv[4][4];
#pragma unroll
  for (int i = 0; i < 4; ++i)
#pragma unroll
    for (int j = 0; j < 4; ++j)
      hv[i][j] = *(const float4*)&Hin[((bq << 2) + i) * 1024 + (kl << 4) + (j << 2)];

  __syncthreads();   // R staged

  float acc[12][4];
#pragma unroll
  for (int c = 0; c < 12; ++c)
#pragma unroll
    for (int i = 0; i < 4; ++i) acc[c][i] = 0.f;

#pragma unroll
  for (int j = 0; j < 4; ++j) {
    const int k = (kl << 4) + (j << 2);
#pragma unroll
    for (int c = 0; c < 12; ++c) {
      float4 rv = *(const float4*)&Rl[swz(c * 1024 + k)];
#pragma unroll
      for (int i = 0; i < 4; ++i) {
        acc[c][i] = fmaf(rv.x, hv[i][j].x, acc[c][i]);
        acc[c][i] = fmaf(rv.y, hv[i][j].y, acc[c][i]);
        acc[c][i] = fmaf(rv.z, hv[i][j].z, acc[c][i]);
        acc[c][i] = fmaf(rv.w, hv[i][j].w, acc[c][i]);
      }
    }
  }

  // 4 phases, one u-column (ul=ch) each: reduce 64-lane k-split via LDS, then gates
  const int pair = tid >> 3, chunk = tid & 7;   // 8-lane reduce groups
  const int gb = pair & 15;                     // batch handled by this group (16..31 dup)
  const bool isg = (chunk == 0) && (pair < 16);

#pragma unroll
  for (int ch = 0; ch < 4; ++ch) {
    __syncthreads();   // WAR on Red
#pragma unroll
    for (int g = 0; g < 3; ++g)
      *(float4*)&Red[bq * 768 + kl * 12 + (g << 2)] =
          make_float4(acc[ch * 3 + g][0], acc[ch * 3 + g][1],
                      acc[ch * 3 + g][2], acc[ch * 3 + g][3]);
    __syncthreads();
    // sum over 64 kl: 8 serial + 3-step shuffle within the 8-lane group
    float s0 = 0.f, s1 = 0.f, s2 = 0.f;
    {
      const int base = (gb >> 2) * 768 + (gb & 3);
#pragma unroll
      for (int i8 = 0; i8 < 8; ++i8) {
        int off = ((i8 << 3) + chunk) * 12;
        s0 += Red[base + off];
        s1 += Red[base + off + 4];
        s2 += Red[base + off + 8];
      }
    }
#pragma unroll
    for (int d = 4; d >= 1; d >>= 1) {
      s0 += __shfl_down(s0, d);
      s1 += __shfl_down(s1, d);
      s2 += __shfl_down(s2, d);
    }
    if (isg) {
      const int u = u0 + ch;
      const int base = (gb * 255 + t) * U3;
      float xz = xproj[base + u];
      float xr = xproj[base + 1024 + u];
      float xh = xproj[base + 2048 + u];
      float rz = s0 + gbias[3072 + u];
      float rr = s1 + gbias[3072 + 1024 + u];
      float rh = s2 + gbias[3072 + 2048 + u];
      float z  = 1.f / (1.f + __expf(-(xz + rz)));
      float r  = 1.f / (1.f + __expf(-(xr + rr)));
      float hh = tanhf(xh + r * rh);
      float hold = Hin[gb * 1024 + u];
      float hn = fmaf(z, hold - hh, hh);        // z*h + (1-z)*hh
      bool m = (tok[gb * 256 + t] != 0);
      float hw = m ? hn : hold;
      float yprev = (t == 0) ? 0.f : Ybuf[gb * 1024 + u];
      float yn = m ? hn : yprev;
      Hout[gb * 1024 + u] = hw;
      Ybuf[gb * 1024 + u] = yn;
      gout[(size_t)(gb * 255 + t) * 1024 + u] = f2bf(yn);
    }
  }
}

// ---------------- K4: logits = gru_out(bf16) @ out_W(f32->bf16 on the fly) + out_b ----------------
// 128x128 tile, BK=32, 4 waves (2x2), mfma_f32_16x16x32_bf16, double-buffered LDS,
// issue-loads-early / ds-write-late (T14-style) staging.
__global__ __launch_bounds__(256) void k_outproj(const unsigned short* __restrict__ A,
                                                 const float* __restrict__ W,
                                                 const float* __restrict__ ob,
                                                 float* __restrict__ C) {
  __shared__ unsigned short Alds[2][128 * 32];
  __shared__ unsigned short Wlds[2][128 * 40];   // [col][k], padded to 40 for bank spread
  const int tid = threadIdx.x;
  const int rb = blockIdx.x;   // 0..31 row tiles (4096 padded rows)
  const int cb = blockIdx.y;   // 0..249 col tiles
  const int l = tid & 63, wave = tid >> 6;
  const int wm = wave >> 1, wn = wave & 1;
  const int rlane = l & 15, kslc = (l >> 4) << 3;

  const int arow = tid >> 2;            // 0..63
  const int acol = (tid & 3) << 3;      // bf16 elem offset
  const int wc4 = (tid & 31) << 2;      // col group of 4
  const int wkq = (tid >> 5) << 2;      // k group of 4

  f32x4 acc[4][4];
#pragma unroll
  for (int i = 0; i < 4; ++i)
#pragma unroll
    for (int j2 = 0; j2 < 4; ++j2) acc[i][j2] = (f32x4)(0.f);

  int4 av[2];
  float4 wv[4];

  // prologue: stage kt=0
#pragma unroll
  for (int u = 0; u < 2; ++u)
    av[u] = *(const int4*)&A[((size_t)(rb * 128 + arow + u * 64)) * 1024 + acol];
#pragma unroll
  for (int r = 0; r < 4; ++r)
    wv[r] = *(const float4*)&W[(size_t)(wkq + r) * 32000 + cb * 128 + wc4];
#pragma unroll
  for (int u = 0; u < 2; ++u)
    *(int4*)&Alds[0][u * 2048 + tid * 8] = av[u];
#pragma unroll
  for (int cc = 0; cc < 4; ++cc) {
    unsigned p01 = (unsigned)f2bf(((const float*)&wv[0])[cc]) |
                   ((unsigned)f2bf(((const float*)&wv[1])[cc]) << 16);
    unsigned p23 = (unsigned)f2bf(((const float*)&wv[2])[cc]) |
                   ((unsigned)f2bf(((const float*)&wv[3])[cc]) << 16);
    *(uint2*)&Wlds[0][(wc4 + cc) * 40 + wkq] = make_uint2(p01, p23);
  }
  __syncthreads();

  for (int kt = 0; kt < 32; ++kt) {
    const int buf = kt & 1;
    if (kt < 31) {   // issue next-tile global loads early
#pragma unroll
      for (int u = 0; u < 2; ++u)
        av[u] = *(const int4*)&A[((size_t)(rb * 128 + arow + u * 64)) * 1024 +
                                 (kt + 1) * 32 + acol];
#pragma unroll
      for (int r = 0; r < 4; ++r)
        wv[r] = *(const float4*)&W[(size_t)((kt + 1) * 32 + wkq + r) * 32000 +
                                   cb * 128 + wc4];
    }
    s16x8 af[4], bfr[4];
#pragma unroll
    for (int mi = 0; mi < 4; ++mi)
      af[mi] = *(const s16x8*)&Alds[buf][(wm * 64 + mi * 16 + rlane) * 32 + kslc];
#pragma unroll
    for (int ni = 0; ni < 4; ++ni)
      bfr[ni] = *(const s16x8*)&Wlds[buf][(wn * 64 + ni * 16 + rlane) * 40 + kslc];
#pragma unroll
    for (int mi = 0; mi < 4; ++mi)
#pragma unroll
      for (int ni = 0; ni < 4; ++ni)
        acc[mi][ni] =
            __builtin_amdgcn_mfma_f32_16x16x32_bf16(af[mi], bfr[ni], acc[mi][ni], 0, 0, 0);
    if (kt < 31) {   // write staged regs late
      const int nbuf = buf ^ 1;
#pragma unroll
      for (int u = 0; u < 2; ++u)
        *(int4*)&Alds[nbuf][u * 2048 + tid * 8] = av[u];
#pragma unroll
      for (int cc = 0; cc < 4; ++cc) {
        unsigned p01 = (unsigned)f2bf(((const float*)&wv[0])[cc]) |
                       ((unsigned)f2bf(((const float*)&wv[1])[cc]) << 16);
        unsigned p23 = (unsigned)f2bf(((const float*)&wv[2])[cc]) |
                       ((unsigned)f2bf(((const float*)&wv[3])[cc]) << 16);
        *(uint2*)&Wlds[nbuf][(wc4 + cc) * 40 + wkq] = make_uint2(p01, p23);
      }
    }
    __syncthreads();
  }

  // epilogue: C/D layout col=lane&15, row=(lane>>4)*4+reg
#pragma unroll
  for (int ni = 0; ni < 4; ++ni) {
    const int col = cb * 128 + wn * 64 + ni * 16 + rlane;
    const float bb = ob[col];
#pragma unroll
    for (int mi = 0; mi < 4; ++mi) {
#pragma unroll
      for (int r = 0; r < 4; ++r) {
        const int row = rb * 128 + wm * 64 + mi * 16 + ((l >> 4) << 2) + r;
        if (row < 4080)
          C[(size_t)row * 32000 + col] = acc[mi][ni][r] + bb;
      }
    }
  }
}

// ---------------- launch ----------------
extern "C" void kernel_launch(void* const* d_in, const int* in_sizes, int n_in,
                              void* d_out, int out_size, void* d_ws, size_t ws_size,
                              hipStream_t stream) {
  const float* latent = (const float*)d_in[0];
  const int*   tok    = (const int*)d_in[1];     // teacher tokens (int32 per harness)
  const float* emb    = (const float*)d_in[2];
  const float* dW     = (const float*)d_in[3];
  const float* db     = (const float*)d_in[4];
  const float* gk     = (const float*)d_in[5];
  const float* grk    = (const float*)d_in[6];
  const float* gb     = (const float*)d_in[7];
  const float* oW     = (const float*)d_in[8];
  const float* obias  = (const float*)d_in[9];
  float* out = (float*)d_out;
  char* ws = (char*)d_ws;

  float* xproj = (float*)(ws + WS_XPROJ);
  float* RT    = (float*)(ws + WS_RT);
  float* H     = (float*)(ws + WS_H);
  unsigned short* gout = (unsigned short*)(ws + WS_GOUT);
  float* Ybuf  = (float*)(ws + WS_Y);

  k_transpose<<<dim3(96, 32), 256, 0, stream>>>(grk, RT);
  k_h0<<<64, 256, 0, stream>>>(latent, dW, db, H);
  k_xproj<<<dim3(6, 255), 128, 0, stream>>>(tok, emb, gk, gb, xproj);

  // 255 sequential step launches; kernel boundary provides the grid-wide sync.
  for (int t = 0; t < 255; ++t) {
    const float* Hin = H + (t & 1) * 16384;
    float*       Hout = H + ((t + 1) & 1) * 16384;
    k_step<<<256, 256, 0, stream>>>(RT, xproj, gb, tok, Hin, Hout, Ybuf, gout, t);
  }

  k_outproj<<<dim3(32, 250), 256, 0, stream>>>(gout, oW, obias, out);
}